// Round 1
// baseline (1081.154 us; speedup 1.0000x reference)
//
#include <hip/hip_runtime.h>

using short8 = __attribute__((ext_vector_type(8))) short;
using f32x4  = __attribute__((ext_vector_type(4))) float;

#define SEQ   2048
#define NDIM  4096
#define NH    32
#define NKV   8
#define HD    128
#define ATT_SCALE 0.08838834764831845f   // 1/sqrt(128)

// fp32 -> bf16 (RNE)
static __device__ __forceinline__ unsigned short f2bf(float f) {
    unsigned int u = __float_as_uint(f);
    u += 0x7fffu + ((u >> 16) & 1u);
    return (unsigned short)(u >> 16);
}

// async global->LDS, 16B per lane; LDS dest = wave-uniform base + lane*16
static __device__ __forceinline__ void gload16(const unsigned short* g, unsigned short* l) {
    __builtin_amdgcn_global_load_lds((const __attribute__((address_space(1))) unsigned int*)g,
                                     (__attribute__((address_space(3))) unsigned int*)l,
                                     16, 0, 0);
}

__global__ __launch_bounds__(256) void cvt_kernel(const float* __restrict__ src,
                                                  unsigned short* __restrict__ dst, int n) {
    int i = blockIdx.x * blockDim.x + threadIdx.x;
    if (i * 4 >= n) return;
    float4 v = ((const float4*)src)[i];
    ushort4 o;
    o.x = f2bf(v.x); o.y = f2bf(v.y); o.z = f2bf(v.z); o.w = f2bf(v.w);
    ((ushort4*)dst)[i] = o;
}

// C[M][N] fp32 = A[M][K] * B[N][K]^T, bf16 inputs. 128x128 tile, BK=32, 4 waves (2x2 of 64x64).
__global__ __launch_bounds__(256) void gemm_bt(const unsigned short* __restrict__ A,
                                               const unsigned short* __restrict__ B,
                                               float* __restrict__ C, int M, int N, int K) {
    __shared__ unsigned short Alds[128 * 32];
    __shared__ unsigned short Blds[128 * 32];
    int tid  = threadIdx.x;
    int wid  = tid >> 6, lane = tid & 63;
    int wr   = wid >> 1, wc  = wid & 1;
    int l15  = lane & 15, hg = lane >> 4;
    long mbase = (long)blockIdx.y * 128;
    long nbase = (long)blockIdx.x * 128;

    f32x4 acc[4][4];
#pragma unroll
    for (int i = 0; i < 4; i++)
#pragma unroll
        for (int j = 0; j < 4; j++) acc[i][j] = f32x4{0.f, 0.f, 0.f, 0.f};

    // staging decomposition: 16 chunks of 1KB (64 lanes x 16B); wave w owns chunks {2w, 2w+1} of A and B
    int c0 = wid * 2, c1 = wid * 2 + 1;
    int srow0 = c0 * 16 + (lane >> 2);      // LDS row = chunk*16 + lane/4  ([128][32] bf16, 64B rows)
    int srow1 = c1 * 16 + (lane >> 2);
    int scol  = (lane & 3) * 8;             // bf16 col within row
    const unsigned short* Ap0 = A + (mbase + srow0) * (long)K + scol;
    const unsigned short* Ap1 = A + (mbase + srow1) * (long)K + scol;
    const unsigned short* Bp0 = B + (nbase + srow0) * (long)K + scol;
    const unsigned short* Bp1 = B + (nbase + srow1) * (long)K + scol;

    for (int k0 = 0; k0 < K; k0 += 32) {
        __syncthreads();
        gload16(Ap0 + k0, &Alds[c0 * 512]);
        gload16(Ap1 + k0, &Alds[c1 * 512]);
        gload16(Bp0 + k0, &Blds[c0 * 512]);
        gload16(Bp1 + k0, &Blds[c1 * 512]);
        __syncthreads();

        short8 af[4], bf[4];
#pragma unroll
        for (int mi = 0; mi < 4; mi++)
            af[mi] = *(const short8*)&Alds[(wr * 64 + mi * 16 + l15) * 32 + hg * 8];
#pragma unroll
        for (int ni = 0; ni < 4; ni++)
            bf[ni] = *(const short8*)&Blds[(wc * 64 + ni * 16 + l15) * 32 + hg * 8];
#pragma unroll
        for (int mi = 0; mi < 4; mi++)
#pragma unroll
            for (int ni = 0; ni < 4; ni++)
                acc[mi][ni] = __builtin_amdgcn_mfma_f32_16x16x32_bf16(af[mi], bf[ni], acc[mi][ni], 0, 0, 0);
    }

#pragma unroll
    for (int mi = 0; mi < 4; mi++) {
        long row = mbase + wr * 64 + mi * 16 + hg * 4;
#pragma unroll
        for (int ni = 0; ni < 4; ni++) {
            long col = nbase + wc * 64 + ni * 16 + l15;
            float* cp = C + row * N + col;
#pragma unroll
            for (int r = 0; r < 4; r++) cp[(long)r * N] = acc[mi][ni][r];
        }
    }
}

// RoPE on interleaved pairs; writes bf16 (scale folded in for Q).
__global__ __launch_bounds__(256) void rope_kernel(const float* __restrict__ X,
                                                   const float* __restrict__ cosb,
                                                   const float* __restrict__ sinb,
                                                   unsigned short* __restrict__ out,
                                                   int hmask, int sshift, int rowstride, float scale) {
    int i = blockIdx.x * blockDim.x + threadIdx.x;
    int p = i & 63;
    int h = (i >> 6) & hmask;
    int s = i >> sshift;
    long off = (long)s * rowstride + h * 128 + 2 * p;
    float2 q = *(const float2*)(X + off);
    float c  = cosb[s * 64 + p];
    float si = sinb[s * 64 + p];
    float oe = (q.x * c - q.y * si) * scale;
    float oo = (q.x * si + q.y * c) * scale;
    ushort2 o;
    o.x = f2bf(oe); o.y = f2bf(oo);
    *(ushort2*)(out + off) = o;
}

// V [2048][1024] fp32 -> V^T [1024][2048] bf16 (flat: (head*128+d)*2048 + s)
__global__ void transpose_v(const float* __restrict__ V, unsigned short* __restrict__ VT) {
    __shared__ float tile[32][33];
    int bs = blockIdx.x * 32, bc = blockIdx.y * 32;
    int tx = threadIdx.x, ty = threadIdx.y;
#pragma unroll
    for (int r = 0; r < 4; r++)
        tile[ty + r * 8][tx] = V[(long)(bs + ty + r * 8) * 1024 + bc + tx];
    __syncthreads();
#pragma unroll
    for (int r = 0; r < 4; r++)
        VT[(long)(bc + ty + r * 8) * 2048 + bs + tx] = f2bf(tile[tx][ty + r * 8]);
}

// Flash attention. 1 wave per (head, 16 q rows). Swapped QK^T (S^T = K*Q^T) so softmax
// stats and O accumulator are both indexed by q = lane&15. KV block = 32.
__global__ __launch_bounds__(64) void attn_kernel(const unsigned short* __restrict__ Q,
                                                  const unsigned short* __restrict__ Kb,
                                                  const unsigned short* __restrict__ VT,
                                                  unsigned short* __restrict__ O) {
    __shared__ __align__(16) unsigned short Plds[16 * 32];
    int head = blockIdx.x >> 7;
    int qblk = blockIdx.x & 127;
    int kvh  = head >> 2;
    int lane = threadIdx.x;
    int l15  = lane & 15, hg = lane >> 4;
    int qg   = qblk * 16 + l15;

    // Q fragments (B operand of S^T mfma): Q[qg][c*32 + hg*8 + j], scale pre-folded
    short8 qf[4];
    const unsigned short* qrow = Q + (long)qg * NDIM + head * 128;
#pragma unroll
    for (int c = 0; c < 4; c++) qf[c] = *(const short8*)(qrow + c * 32 + hg * 8);

    f32x4 acc[8];   // O[q=l15][d = 16*t2 + hg*4 + r]
#pragma unroll
    for (int t = 0; t < 8; t++) acc[t] = f32x4{0.f, 0.f, 0.f, 0.f};
    float m_run = -INFINITY, l_run = 0.f;

    const unsigned short* Kbase = Kb + kvh * 128;               // row stride 1024
    const unsigned short* Vbase = VT + (long)kvh * 128 * 2048;  // [d][s]

    int nblk = (qblk + 2) >> 1;   // cover kv 0 .. qblk*16+15
    for (int b = 0; b < nblk; b++) {
        int kv0 = b * 32;
        // S^T tiles: lane holds S[q=qg][kv = kv0 + 16t + hg*4 + r]
        f32x4 st[2];
#pragma unroll
        for (int t = 0; t < 2; t++) {
            f32x4 s = f32x4{0.f, 0.f, 0.f, 0.f};
            const unsigned short* krow = Kbase + (long)(kv0 + t * 16 + l15) * (NKV * HD);
#pragma unroll
            for (int c = 0; c < 4; c++) {
                short8 kf = *(const short8*)(krow + c * 32 + hg * 8);
                s = __builtin_amdgcn_mfma_f32_16x16x32_bf16(kf, qf[c], s, 0, 0, 0);
            }
            st[t] = s;
        }
        // causal mask + row max
        float pmax = -INFINITY;
#pragma unroll
        for (int t = 0; t < 2; t++)
#pragma unroll
            for (int r = 0; r < 4; r++) {
                int kv = kv0 + t * 16 + hg * 4 + r;
                float v = st[t][r];
                if (kv > qg) v = -INFINITY;
                st[t][r] = v;
                pmax = fmaxf(pmax, v);
            }
        pmax = fmaxf(pmax, __shfl_xor(pmax, 16));
        pmax = fmaxf(pmax, __shfl_xor(pmax, 32));
        float m_new = fmaxf(m_run, pmax);
        float corr  = __expf(m_run - m_new);
        float pv[2][4];
        float psum = 0.f;
#pragma unroll
        for (int t = 0; t < 2; t++)
#pragma unroll
            for (int r = 0; r < 4; r++) {
                float e = __expf(st[t][r] - m_new);
                pv[t][r] = e;
                psum += e;
            }
        psum += __shfl_xor(psum, 16);
        psum += __shfl_xor(psum, 32);
        l_run = l_run * corr + psum;
        m_run = m_new;
#pragma unroll
        for (int t = 0; t < 8; t++) acc[t] *= corr;

        // P -> LDS: P[q=l15][kv_local = 16t + hg*4 + r] bf16
#pragma unroll
        for (int t = 0; t < 2; t++) {
            ushort4 pk;
            pk.x = f2bf(pv[t][0]); pk.y = f2bf(pv[t][1]);
            pk.z = f2bf(pv[t][2]); pk.w = f2bf(pv[t][3]);
            *(ushort4*)&Plds[l15 * 32 + t * 16 + hg * 4] = pk;
        }
        __syncthreads();
        // P^T B-fragment: P[q=l15][kv = hg*8 + j]
        short8 pf = *(const short8*)&Plds[l15 * 32 + hg * 8];
        __syncthreads();

        // O^T += V^T * P^T : A-frag = V^T[d0+l15][kv0 + hg*8 + j] (contiguous 16B)
#pragma unroll
        for (int t2 = 0; t2 < 8; t2++) {
            short8 vf = *(const short8*)(Vbase + (long)(t2 * 16 + l15) * 2048 + kv0 + hg * 8);
            acc[t2] = __builtin_amdgcn_mfma_f32_16x16x32_bf16(vf, pf, acc[t2], 0, 0, 0);
        }
    }

    float inv = 1.f / l_run;
    unsigned short* orow = O + (long)qg * NDIM + head * 128;
#pragma unroll
    for (int t2 = 0; t2 < 8; t2++) {
        ushort4 o4;
        o4.x = f2bf(acc[t2][0] * inv); o4.y = f2bf(acc[t2][1] * inv);
        o4.z = f2bf(acc[t2][2] * inv); o4.w = f2bf(acc[t2][3] * inv);
        *(ushort4*)(orow + t2 * 16 + hg * 4) = o4;
    }
}

extern "C" void kernel_launch(void* const* d_in, const int* in_sizes, int n_in,
                              void* d_out, int out_size, void* d_ws, size_t ws_size,
                              hipStream_t stream) {
    const float* x  = (const float*)d_in[0];
    const float* fc = (const float*)d_in[1];
    const float* fs = (const float*)d_in[2];
    const float* wq = (const float*)d_in[3];
    const float* wk = (const float*)d_in[4];
    const float* wv = (const float*)d_in[5];
    const float* wo = (const float*)d_in[6];
    float* out = (float*)d_out;
    char* ws = (char*)d_ws;
    const size_t MB = 1024 * 1024;
    // workspace layout (152 MB total):
    unsigned short* x_bf  = (unsigned short*)(ws + 0);        // 16MB, reused as Qbf after QKV GEMMs
    unsigned short* wq_bf = (unsigned short*)(ws + 16 * MB);  // 32MB
    unsigned short* wk_bf = (unsigned short*)(ws + 48 * MB);  // 8MB
    unsigned short* wv_bf = (unsigned short*)(ws + 56 * MB);  // 8MB
    unsigned short* wo_bf = (unsigned short*)(ws + 64 * MB);  // 32MB
    unsigned short* Kbf   = (unsigned short*)(ws + 96 * MB);  // 4MB
    unsigned short* VT    = (unsigned short*)(ws + 100 * MB); // 4MB
    float* Q32 = (float*)(ws + 104 * MB);                     // 32MB
    float* K32 = (float*)(ws + 136 * MB);                     // 8MB
    float* V32 = (float*)(ws + 144 * MB);                     // 8MB
    unsigned short* Qbf     = x_bf;                           // alias: x_bf dead after QKV GEMMs
    unsigned short* attn_bf = (unsigned short*)(ws + 104 * MB); // alias: Q32 dead after rope

    // 1) fp32 -> bf16
    cvt_kernel<<<8192, 256, 0, stream>>>(x, x_bf, SEQ * NDIM);
    cvt_kernel<<<16384, 256, 0, stream>>>(wq, wq_bf, NDIM * NDIM);
    cvt_kernel<<<4096, 256, 0, stream>>>(wk, wk_bf, NKV * HD * NDIM);
    cvt_kernel<<<4096, 256, 0, stream>>>(wv, wv_bf, NKV * HD * NDIM);
    cvt_kernel<<<16384, 256, 0, stream>>>(wo, wo_bf, NDIM * NDIM);

    // 2) QKV projections (fp32 out)
    gemm_bt<<<dim3(NDIM / 128, SEQ / 128), 256, 0, stream>>>(x_bf, wq_bf, Q32, SEQ, NDIM, NDIM);
    gemm_bt<<<dim3((NKV * HD) / 128, SEQ / 128), 256, 0, stream>>>(x_bf, wk_bf, K32, SEQ, NKV * HD, NDIM);
    gemm_bt<<<dim3((NKV * HD) / 128, SEQ / 128), 256, 0, stream>>>(x_bf, wv_bf, V32, SEQ, NKV * HD, NDIM);

    // 3) RoPE (+ scale fold for Q) and V transpose, all to bf16
    rope_kernel<<<16384, 256, 0, stream>>>(Q32, fc, fs, Qbf, 31, 11, NDIM, ATT_SCALE);
    rope_kernel<<<4096, 256, 0, stream>>>(K32, fc, fs, Kbf, 7, 9, NKV * HD, 1.0f);
    transpose_v<<<dim3(SEQ / 32, (NKV * HD) / 32), dim3(32, 8), 0, stream>>>(V32, VT);

    // 4) causal GQA flash attention
    attn_kernel<<<NH * (SEQ / 16), 64, 0, stream>>>(Qbf, Kbf, VT, attn_bf);

    // 5) output projection (fp32 out = d_out)
    gemm_bt<<<dim3(NDIM / 128, SEQ / 128), 256, 0, stream>>>(attn_bf, wo_bf, out, SEQ, NDIM, NDIM);
}

// Round 2
// 776.491 us; speedup vs baseline: 1.3924x; 1.3924x over previous
//
#include <hip/hip_runtime.h>

using short8 = __attribute__((ext_vector_type(8))) short;
using f32x4  = __attribute__((ext_vector_type(4))) float;

#define SEQ   2048
#define NDIM  4096
#define NH    32
#define NKV   8
#define HD    128
#define ATT_SCALE 0.08838834764831845f   // 1/sqrt(128)

// fp32 -> bf16 (RNE)
static __device__ __forceinline__ unsigned short f2bf(float f) {
    unsigned int u = __float_as_uint(f);
    u += 0x7fffu + ((u >> 16) & 1u);
    return (unsigned short)(u >> 16);
}

// async global->LDS, 16B per lane; LDS dest = wave-uniform base + lane*16
static __device__ __forceinline__ void gload16(const unsigned short* g, unsigned short* l) {
    __builtin_amdgcn_global_load_lds((const __attribute__((address_space(1))) unsigned int*)g,
                                     (__attribute__((address_space(3))) unsigned int*)l,
                                     16, 0, 0);
}

__global__ __launch_bounds__(256) void cvt_kernel(const float* __restrict__ src,
                                                  unsigned short* __restrict__ dst, int n) {
    int i = blockIdx.x * blockDim.x + threadIdx.x;
    if (i * 4 >= n) return;
    float4 v = ((const float4*)src)[i];
    ushort4 o;
    o.x = f2bf(v.x); o.y = f2bf(v.y); o.z = f2bf(v.z); o.w = f2bf(v.w);
    ((ushort4*)dst)[i] = o;
}

// C[M][N] fp32 = A[M][K] * B[N][K]^T, bf16 inputs. 128x128 tile, BK=32, 4 waves (2x2 of 64x64).
__global__ __launch_bounds__(256) void gemm_bt(const unsigned short* __restrict__ A,
                                               const unsigned short* __restrict__ B,
                                               float* __restrict__ C, int M, int N, int K) {
    __shared__ unsigned short Alds[128 * 32];
    __shared__ unsigned short Blds[128 * 32];
    int tid  = threadIdx.x;
    int wid  = tid >> 6, lane = tid & 63;
    int wr   = wid >> 1, wc  = wid & 1;
    int l15  = lane & 15, hg = lane >> 4;
    long mbase = (long)blockIdx.y * 128;
    long nbase = (long)blockIdx.x * 128;

    f32x4 acc[4][4];
#pragma unroll
    for (int i = 0; i < 4; i++)
#pragma unroll
        for (int j = 0; j < 4; j++) acc[i][j] = f32x4{0.f, 0.f, 0.f, 0.f};

    int c0 = wid * 2, c1 = wid * 2 + 1;
    int srow0 = c0 * 16 + (lane >> 2);
    int srow1 = c1 * 16 + (lane >> 2);
    int scol  = (lane & 3) * 8;
    const unsigned short* Ap0 = A + (mbase + srow0) * (long)K + scol;
    const unsigned short* Ap1 = A + (mbase + srow1) * (long)K + scol;
    const unsigned short* Bp0 = B + (nbase + srow0) * (long)K + scol;
    const unsigned short* Bp1 = B + (nbase + srow1) * (long)K + scol;

    for (int k0 = 0; k0 < K; k0 += 32) {
        __syncthreads();
        gload16(Ap0 + k0, &Alds[c0 * 512]);
        gload16(Ap1 + k0, &Alds[c1 * 512]);
        gload16(Bp0 + k0, &Blds[c0 * 512]);
        gload16(Bp1 + k0, &Blds[c1 * 512]);
        __syncthreads();

        short8 af[4], bf[4];
#pragma unroll
        for (int mi = 0; mi < 4; mi++)
            af[mi] = *(const short8*)&Alds[(wr * 64 + mi * 16 + l15) * 32 + hg * 8];
#pragma unroll
        for (int ni = 0; ni < 4; ni++)
            bf[ni] = *(const short8*)&Blds[(wc * 64 + ni * 16 + l15) * 32 + hg * 8];
#pragma unroll
        for (int mi = 0; mi < 4; mi++)
#pragma unroll
            for (int ni = 0; ni < 4; ni++)
                acc[mi][ni] = __builtin_amdgcn_mfma_f32_16x16x32_bf16(af[mi], bf[ni], acc[mi][ni], 0, 0, 0);
    }

#pragma unroll
    for (int mi = 0; mi < 4; mi++) {
        long row = mbase + wr * 64 + mi * 16 + hg * 4;
#pragma unroll
        for (int ni = 0; ni < 4; ni++) {
            long col = nbase + wc * 64 + ni * 16 + l15;
            float* cp = C + row * N + col;
#pragma unroll
            for (int r = 0; r < 4; r++) cp[(long)r * N] = acc[mi][ni][r];
        }
    }
}

// RoPE on interleaved pairs; writes bf16 (scale folded in for Q).
__global__ __launch_bounds__(256) void rope_kernel(const float* __restrict__ X,
                                                   const float* __restrict__ cosb,
                                                   const float* __restrict__ sinb,
                                                   unsigned short* __restrict__ out,
                                                   int hmask, int sshift, int rowstride, float scale) {
    int i = blockIdx.x * blockDim.x + threadIdx.x;
    int p = i & 63;
    int h = (i >> 6) & hmask;
    int s = i >> sshift;
    long off = (long)s * rowstride + h * 128 + 2 * p;
    float2 q = *(const float2*)(X + off);
    float c  = cosb[s * 64 + p];
    float si = sinb[s * 64 + p];
    float oe = (q.x * c - q.y * si) * scale;
    float oo = (q.x * si + q.y * c) * scale;
    ushort2 o;
    o.x = f2bf(oe); o.y = f2bf(oo);
    *(ushort2*)(out + off) = o;
}

// V [2048][1024] fp32 -> V^T [1024][2048] bf16 (flat: (head*128+d)*2048 + s)
__global__ void transpose_v(const float* __restrict__ V, unsigned short* __restrict__ VT) {
    __shared__ float tile[32][33];
    int bs = blockIdx.x * 32, bc = blockIdx.y * 32;
    int tx = threadIdx.x, ty = threadIdx.y;
#pragma unroll
    for (int r = 0; r < 4; r++)
        tile[ty + r * 8][tx] = V[(long)(bs + ty + r * 8) * 1024 + bc + tx];
    __syncthreads();
#pragma unroll
    for (int r = 0; r < 4; r++)
        VT[(long)(bc + ty + r * 8) * 2048 + bs + tx] = f2bf(tile[tx][ty + r * 8]);
}

// ---------------- Flash attention v2 ----------------
// 1 wave per (head, 32 q rows). No barriers (single-wave workgroup; same-wave LDS ops
// are in-order). Double-buffered K register prefetch; V loads issued before QK MFMAs.
// Swapped QK^T (S^T = K*Q^T): softmax stats & O accumulator indexed by q = lane&15.
struct KReg { short8 f[2][4]; };

static __device__ __forceinline__ void load_k(KReg& kr, const unsigned short* Kbase,
                                              int kv0, int l15, int hg) {
#pragma unroll
    for (int kt = 0; kt < 2; kt++)
#pragma unroll
        for (int c = 0; c < 4; c++)
            kr.f[kt][c] = *(const short8*)(Kbase + (long)(kv0 + kt * 16 + l15) * (NKV * HD) + c * 32 + hg * 8);
}

__global__ __launch_bounds__(64) void attn_kernel(const unsigned short* __restrict__ Q,
                                                  const unsigned short* __restrict__ Kb,
                                                  const unsigned short* __restrict__ VT,
                                                  unsigned short* __restrict__ O) {
    __shared__ __align__(16) unsigned short Plds[2][16][40];  // padded stride: 80B rows
    int bid  = blockIdx.x;
    int kvh  = bid & 7;                     // kvh == XCD under %8 round-robin dispatch
    int head = kvh * 4 + ((bid >> 3) & 3);
    int qblk = bid >> 5;                    // 64 q-tiles of 32 rows
    int lane = threadIdx.x;
    int l15  = lane & 15, hg = lane >> 4;
    int qbase = qblk * 32;

    // Q fragments (B operand): Q[q = qbase + qt*16 + l15][c*32 + hg*8 + j]
    short8 qf[2][4];
#pragma unroll
    for (int qt = 0; qt < 2; qt++) {
        const unsigned short* qrow = Q + (long)(qbase + qt * 16 + l15) * NDIM + head * 128;
#pragma unroll
        for (int c = 0; c < 4; c++) qf[qt][c] = *(const short8*)(qrow + c * 32 + hg * 8);
    }

    f32x4 acc[2][8];  // acc[qt][t2]: O^T[d = t2*16 + hg*4 + r][q = l15]
#pragma unroll
    for (int qt = 0; qt < 2; qt++)
#pragma unroll
        for (int t = 0; t < 8; t++) acc[qt][t] = f32x4{0.f, 0.f, 0.f, 0.f};
    float m_run[2] = {-INFINITY, -INFINITY};
    float l_run[2] = {0.f, 0.f};

    const unsigned short* Kbase = Kb + kvh * 128;               // row stride 1024
    const unsigned short* Vbase = VT + (long)kvh * 128 * 2048;  // [d][s]

    int nblk = qblk + 1;   // KV blocks of 32 covering kv <= qbase+31
    KReg k0, k1;
    load_k(k0, Kbase, 0, l15, hg);

#define ATT_STEP(KC, KN, bb) do {                                                     \
    int kv0 = (bb) * 32;                                                              \
    /* V fragments for this block (A operand of PV), issued early */                  \
    short8 vf[8];                                                                     \
    _Pragma("unroll")                                                                 \
    for (int t2 = 0; t2 < 8; t2++)                                                    \
        vf[t2] = *(const short8*)(Vbase + (long)(t2 * 16 + l15) * 2048 + kv0 + hg * 8); \
    /* prefetch next K block (clamped addr -> always in-bounds, no branch) */         \
    int kvn = kv0 + 32 > SEQ - 32 ? SEQ - 32 : kv0 + 32;                              \
    load_k(KN, Kbase, kvn, l15, hg);                                                  \
    /* S^T tiles: st[qt][kt][r] = S[q][kv = kv0 + kt*16 + hg*4 + r] */                \
    f32x4 st[2][2];                                                                   \
    _Pragma("unroll")                                                                 \
    for (int qt = 0; qt < 2; qt++)                                                    \
        _Pragma("unroll")                                                             \
        for (int kt = 0; kt < 2; kt++) {                                              \
            f32x4 s = f32x4{0.f, 0.f, 0.f, 0.f};                                      \
            _Pragma("unroll")                                                         \
            for (int c = 0; c < 4; c++)                                               \
                s = __builtin_amdgcn_mfma_f32_16x16x32_bf16(KC.f[kt][c], qf[qt][c], s, 0, 0, 0); \
            st[qt][kt] = s;                                                           \
        }                                                                             \
    _Pragma("unroll")                                                                 \
    for (int qt = 0; qt < 2; qt++) {                                                  \
        int qg = qbase + qt * 16 + l15;                                               \
        float pmax = -INFINITY;                                                       \
        _Pragma("unroll")                                                             \
        for (int kt = 0; kt < 2; kt++)                                                \
            _Pragma("unroll")                                                         \
            for (int r = 0; r < 4; r++) {                                             \
                int kv = kv0 + kt * 16 + hg * 4 + r;                                  \
                float v = st[qt][kt][r];                                              \
                if (kv > qg) v = -INFINITY;                                           \
                st[qt][kt][r] = v;                                                    \
                pmax = fmaxf(pmax, v);                                                \
            }                                                                         \
        pmax = fmaxf(pmax, __shfl_xor(pmax, 16));                                     \
        pmax = fmaxf(pmax, __shfl_xor(pmax, 32));                                     \
        float m_new = fmaxf(m_run[qt], pmax);                                         \
        float corr  = __expf(m_run[qt] - m_new);                                      \
        float psum  = 0.f;                                                            \
        ushort4 pk[2];                                                                \
        _Pragma("unroll")                                                             \
        for (int kt = 0; kt < 2; kt++) {                                              \
            float e0 = __expf(st[qt][kt][0] - m_new);                                 \
            float e1 = __expf(st[qt][kt][1] - m_new);                                 \
            float e2 = __expf(st[qt][kt][2] - m_new);                                 \
            float e3 = __expf(st[qt][kt][3] - m_new);                                 \
            psum += e0 + e1 + e2 + e3;                                                \
            pk[kt].x = f2bf(e0); pk[kt].y = f2bf(e1);                                 \
            pk[kt].z = f2bf(e2); pk[kt].w = f2bf(e3);                                 \
        }                                                                             \
        psum += __shfl_xor(psum, 16);                                                 \
        psum += __shfl_xor(psum, 32);                                                 \
        l_run[qt] = l_run[qt] * corr + psum;                                          \
        m_run[qt] = m_new;                                                            \
        _Pragma("unroll")                                                             \
        for (int t2 = 0; t2 < 8; t2++) acc[qt][t2] *= corr;                           \
        _Pragma("unroll")                                                             \
        for (int kt = 0; kt < 2; kt++)                                                \
            *(ushort4*)&Plds[qt][l15][kt * 16 + hg * 4] = pk[kt];                     \
    }                                                                                 \
    /* P^T B-fragment from LDS (same-wave in-order: no barrier), then PV */           \
    _Pragma("unroll")                                                                 \
    for (int qt = 0; qt < 2; qt++) {                                                  \
        short8 pf = *(const short8*)&Plds[qt][l15][hg * 8];                           \
        _Pragma("unroll")                                                             \
        for (int t2 = 0; t2 < 8; t2++)                                                \
            acc[qt][t2] = __builtin_amdgcn_mfma_f32_16x16x32_bf16(vf[t2], pf, acc[qt][t2], 0, 0, 0); \
    }                                                                                 \
} while (0)

    for (int b = 0; b < nblk; b += 2) {
        ATT_STEP(k0, k1, b);
        if (b + 1 < nblk) ATT_STEP(k1, k0, b + 1);
    }
#undef ATT_STEP

#pragma unroll
    for (int qt = 0; qt < 2; qt++) {
        float inv = 1.f / l_run[qt];
        unsigned short* orow = O + (long)(qbase + qt * 16 + l15) * NDIM + head * 128;
#pragma unroll
        for (int t2 = 0; t2 < 8; t2++) {
            ushort4 o4;
            o4.x = f2bf(acc[qt][t2][0] * inv); o4.y = f2bf(acc[qt][t2][1] * inv);
            o4.z = f2bf(acc[qt][t2][2] * inv); o4.w = f2bf(acc[qt][t2][3] * inv);
            *(ushort4*)(orow + t2 * 16 + hg * 4) = o4;
        }
    }
}

extern "C" void kernel_launch(void* const* d_in, const int* in_sizes, int n_in,
                              void* d_out, int out_size, void* d_ws, size_t ws_size,
                              hipStream_t stream) {
    const float* x  = (const float*)d_in[0];
    const float* fc = (const float*)d_in[1];
    const float* fs = (const float*)d_in[2];
    const float* wq = (const float*)d_in[3];
    const float* wk = (const float*)d_in[4];
    const float* wv = (const float*)d_in[5];
    const float* wo = (const float*)d_in[6];
    float* out = (float*)d_out;
    char* ws = (char*)d_ws;
    const size_t MB = 1024 * 1024;
    unsigned short* x_bf  = (unsigned short*)(ws + 0);        // 16MB, reused as Qbf
    unsigned short* wq_bf = (unsigned short*)(ws + 16 * MB);  // 32MB
    unsigned short* wk_bf = (unsigned short*)(ws + 48 * MB);  // 8MB
    unsigned short* wv_bf = (unsigned short*)(ws + 56 * MB);  // 8MB
    unsigned short* wo_bf = (unsigned short*)(ws + 64 * MB);  // 32MB
    unsigned short* Kbf   = (unsigned short*)(ws + 96 * MB);  // 4MB
    unsigned short* VT    = (unsigned short*)(ws + 100 * MB); // 4MB
    float* Q32 = (float*)(ws + 104 * MB);                     // 32MB
    float* K32 = (float*)(ws + 136 * MB);                     // 8MB
    float* V32 = (float*)(ws + 144 * MB);                     // 8MB
    unsigned short* Qbf     = x_bf;                           // alias: x_bf dead after QKV GEMMs
    unsigned short* attn_bf = (unsigned short*)(ws + 104 * MB); // alias: Q32 dead after rope

    cvt_kernel<<<8192, 256, 0, stream>>>(x, x_bf, SEQ * NDIM);
    cvt_kernel<<<16384, 256, 0, stream>>>(wq, wq_bf, NDIM * NDIM);
    cvt_kernel<<<4096, 256, 0, stream>>>(wk, wk_bf, NKV * HD * NDIM);
    cvt_kernel<<<4096, 256, 0, stream>>>(wv, wv_bf, NKV * HD * NDIM);
    cvt_kernel<<<16384, 256, 0, stream>>>(wo, wo_bf, NDIM * NDIM);

    gemm_bt<<<dim3(NDIM / 128, SEQ / 128), 256, 0, stream>>>(x_bf, wq_bf, Q32, SEQ, NDIM, NDIM);
    gemm_bt<<<dim3((NKV * HD) / 128, SEQ / 128), 256, 0, stream>>>(x_bf, wk_bf, K32, SEQ, NKV * HD, NDIM);
    gemm_bt<<<dim3((NKV * HD) / 128, SEQ / 128), 256, 0, stream>>>(x_bf, wv_bf, V32, SEQ, NKV * HD, NDIM);

    rope_kernel<<<16384, 256, 0, stream>>>(Q32, fc, fs, Qbf, 31, 11, NDIM, ATT_SCALE);
    rope_kernel<<<4096, 256, 0, stream>>>(K32, fc, fs, Kbf, 7, 9, NKV * HD, 1.0f);
    transpose_v<<<dim3(SEQ / 32, (NKV * HD) / 32), dim3(32, 8), 0, stream>>>(V32, VT);

    attn_kernel<<<NH * (SEQ / 32), 64, 0, stream>>>(Qbf, Kbf, VT, attn_bf);

    gemm_bt<<<dim3(NDIM / 128, SEQ / 128), 256, 0, stream>>>(attn_bf, wo_bf, out, SEQ, NDIM, NDIM);
}

// Round 3
// 667.422 us; speedup vs baseline: 1.6199x; 1.1634x over previous
//
#include <hip/hip_runtime.h>

using short8 = __attribute__((ext_vector_type(8))) short;
using f32x4  = __attribute__((ext_vector_type(4))) float;

#define SEQ   2048
#define NDIM  4096
#define NH    32
#define NKV   8
#define HD    128
#define ATT_SCALE 0.08838834764831845f   // 1/sqrt(128)

// fp32 -> bf16 (RNE)
static __device__ __forceinline__ unsigned short f2bf(float f) {
    unsigned int u = __float_as_uint(f);
    u += 0x7fffu + ((u >> 16) & 1u);
    return (unsigned short)(u >> 16);
}

// async global->LDS, 16B per lane; LDS dest = wave-uniform base + lane*16
static __device__ __forceinline__ void gload16(const unsigned short* g, unsigned short* l) {
    __builtin_amdgcn_global_load_lds((const __attribute__((address_space(1))) unsigned int*)g,
                                     (__attribute__((address_space(3))) unsigned int*)l,
                                     16, 0, 0);
}

__global__ __launch_bounds__(256) void cvt_kernel(const float* __restrict__ src,
                                                  unsigned short* __restrict__ dst, int n) {
    int i = blockIdx.x * blockDim.x + threadIdx.x;
    if (i * 4 >= n) return;
    float4 v = ((const float4*)src)[i];
    ushort4 o;
    o.x = f2bf(v.x); o.y = f2bf(v.y); o.z = f2bf(v.z); o.w = f2bf(v.w);
    ((ushort4*)dst)[i] = o;
}

// C[M][N] fp32 = A[M][K] * B[N][K]^T, bf16 inputs. 128x128 tile, BK=32, 4 waves (2x2 of 64x64).
__global__ __launch_bounds__(256) void gemm_bt(const unsigned short* __restrict__ A,
                                               const unsigned short* __restrict__ B,
                                               float* __restrict__ C, int M, int N, int K) {
    __shared__ unsigned short Alds[128 * 32];
    __shared__ unsigned short Blds[128 * 32];
    int tid  = threadIdx.x;
    int wid  = tid >> 6, lane = tid & 63;
    int wr   = wid >> 1, wc  = wid & 1;
    int l15  = lane & 15, hg = lane >> 4;
    long mbase = (long)blockIdx.y * 128;
    long nbase = (long)blockIdx.x * 128;

    f32x4 acc[4][4];
#pragma unroll
    for (int i = 0; i < 4; i++)
#pragma unroll
        for (int j = 0; j < 4; j++) acc[i][j] = f32x4{0.f, 0.f, 0.f, 0.f};

    int c0 = wid * 2, c1 = wid * 2 + 1;
    int srow0 = c0 * 16 + (lane >> 2);
    int srow1 = c1 * 16 + (lane >> 2);
    int scol  = (lane & 3) * 8;
    const unsigned short* Ap0 = A + (mbase + srow0) * (long)K + scol;
    const unsigned short* Ap1 = A + (mbase + srow1) * (long)K + scol;
    const unsigned short* Bp0 = B + (nbase + srow0) * (long)K + scol;
    const unsigned short* Bp1 = B + (nbase + srow1) * (long)K + scol;

    for (int k0 = 0; k0 < K; k0 += 32) {
        __syncthreads();
        gload16(Ap0 + k0, &Alds[c0 * 512]);
        gload16(Ap1 + k0, &Alds[c1 * 512]);
        gload16(Bp0 + k0, &Blds[c0 * 512]);
        gload16(Bp1 + k0, &Blds[c1 * 512]);
        __syncthreads();

        short8 af[4], bf[4];
#pragma unroll
        for (int mi = 0; mi < 4; mi++)
            af[mi] = *(const short8*)&Alds[(wr * 64 + mi * 16 + l15) * 32 + hg * 8];
#pragma unroll
        for (int ni = 0; ni < 4; ni++)
            bf[ni] = *(const short8*)&Blds[(wc * 64 + ni * 16 + l15) * 32 + hg * 8];
#pragma unroll
        for (int mi = 0; mi < 4; mi++)
#pragma unroll
            for (int ni = 0; ni < 4; ni++)
                acc[mi][ni] = __builtin_amdgcn_mfma_f32_16x16x32_bf16(af[mi], bf[ni], acc[mi][ni], 0, 0, 0);
    }

#pragma unroll
    for (int mi = 0; mi < 4; mi++) {
        long row = mbase + wr * 64 + mi * 16 + hg * 4;
#pragma unroll
        for (int ni = 0; ni < 4; ni++) {
            long col = nbase + wc * 64 + ni * 16 + l15;
            float* cp = C + row * N + col;
#pragma unroll
            for (int r = 0; r < 4; r++) cp[(long)r * N] = acc[mi][ni][r];
        }
    }
}

// RoPE on interleaved pairs; separate in/out row strides (KV fused buffer); bf16 out.
__global__ __launch_bounds__(256) void rope_kernel(const float* __restrict__ X,
                                                   const float* __restrict__ cosb,
                                                   const float* __restrict__ sinb,
                                                   unsigned short* __restrict__ out,
                                                   int hmask, int sshift, int stride_in,
                                                   int stride_out, float scale) {
    int i = blockIdx.x * blockDim.x + threadIdx.x;
    int p = i & 63;
    int h = (i >> 6) & hmask;
    int s = i >> sshift;
    float2 q = *(const float2*)(X + (long)s * stride_in + h * 128 + 2 * p);
    float c  = cosb[s * 64 + p];
    float si = sinb[s * 64 + p];
    float oe = (q.x * c - q.y * si) * scale;
    float oo = (q.x * si + q.y * c) * scale;
    ushort2 o;
    o.x = f2bf(oe); o.y = f2bf(oo);
    *(ushort2*)(out + (long)s * stride_out + h * 128 + 2 * p) = o;
}

// V cols of fused KV32 [2048][2048] (V = cols 1024..2047) -> V^T [1024][2048] bf16
__global__ void transpose_v(const float* __restrict__ KV, unsigned short* __restrict__ VT) {
    __shared__ float tile[32][33];
    int bs = blockIdx.x * 32, bc = blockIdx.y * 32;
    int tx = threadIdx.x, ty = threadIdx.y;
#pragma unroll
    for (int r = 0; r < 4; r++)
        tile[ty + r * 8][tx] = KV[(long)(bs + ty + r * 8) * 2048 + 1024 + bc + tx];
    __syncthreads();
#pragma unroll
    for (int r = 0; r < 4; r++)
        VT[(long)(bc + ty + r * 8) * 2048 + bs + tx] = f2bf(tile[tx][ty + r * 8]);
}

// ---------------- Flash attention v3 ----------------
// 1 wave per (head, 32 q rows), heavy-first dispatch (reversed qblk so 64-iter blocks
// start first -> no idle tail). No barriers; double-buffered K register prefetch;
// setprio(1) around MFMA clusters (independent 1-wave blocks = m191's win case).
struct KReg { short8 f[2][4]; };

static __device__ __forceinline__ void load_k(KReg& kr, const unsigned short* Kbase,
                                              int kv0, int l15, int hg) {
#pragma unroll
    for (int kt = 0; kt < 2; kt++)
#pragma unroll
        for (int c = 0; c < 4; c++)
            kr.f[kt][c] = *(const short8*)(Kbase + (long)(kv0 + kt * 16 + l15) * (NKV * HD) + c * 32 + hg * 8);
}

__global__ __launch_bounds__(64) void attn_kernel(const unsigned short* __restrict__ Q,
                                                  const unsigned short* __restrict__ Kb,
                                                  const unsigned short* __restrict__ VT,
                                                  unsigned short* __restrict__ O) {
    __shared__ __align__(16) unsigned short Plds[2][16][40];  // padded stride: 80B rows
    int bid  = blockIdx.x;
    int kvh  = bid & 7;                     // kvh == XCD under %8 round-robin dispatch
    int head = kvh * 4 + ((bid >> 3) & 3);
    int qblk = 63 - (bid >> 5);             // heavy-first: largest nblk dispatched first
    int lane = threadIdx.x;
    int l15  = lane & 15, hg = lane >> 4;
    int qbase = qblk * 32;

    short8 qf[2][4];
#pragma unroll
    for (int qt = 0; qt < 2; qt++) {
        const unsigned short* qrow = Q + (long)(qbase + qt * 16 + l15) * NDIM + head * 128;
#pragma unroll
        for (int c = 0; c < 4; c++) qf[qt][c] = *(const short8*)(qrow + c * 32 + hg * 8);
    }

    f32x4 acc[2][8];  // acc[qt][t2]: O^T[d = t2*16 + hg*4 + r][q = l15]
#pragma unroll
    for (int qt = 0; qt < 2; qt++)
#pragma unroll
        for (int t = 0; t < 8; t++) acc[qt][t] = f32x4{0.f, 0.f, 0.f, 0.f};
    float m_run[2] = {-INFINITY, -INFINITY};
    float l_run[2] = {0.f, 0.f};

    const unsigned short* Kbase = Kb + kvh * 128;               // row stride 1024
    const unsigned short* Vbase = VT + (long)kvh * 128 * 2048;  // [d][s]

    int nblk = qblk + 1;
    KReg k0, k1;
    load_k(k0, Kbase, 0, l15, hg);

#define ATT_STEP(KC, KN, bb) do {                                                     \
    int kv0 = (bb) * 32;                                                              \
    short8 vf[8];                                                                     \
    _Pragma("unroll")                                                                 \
    for (int t2 = 0; t2 < 8; t2++)                                                    \
        vf[t2] = *(const short8*)(Vbase + (long)(t2 * 16 + l15) * 2048 + kv0 + hg * 8); \
    int kvn = kv0 + 32 > SEQ - 32 ? SEQ - 32 : kv0 + 32;                              \
    load_k(KN, Kbase, kvn, l15, hg);                                                  \
    f32x4 st[2][2];                                                                   \
    __builtin_amdgcn_s_setprio(1);                                                    \
    _Pragma("unroll")                                                                 \
    for (int qt = 0; qt < 2; qt++)                                                    \
        _Pragma("unroll")                                                             \
        for (int kt = 0; kt < 2; kt++) {                                              \
            f32x4 s = f32x4{0.f, 0.f, 0.f, 0.f};                                      \
            _Pragma("unroll")                                                         \
            for (int c = 0; c < 4; c++)                                               \
                s = __builtin_amdgcn_mfma_f32_16x16x32_bf16(KC.f[kt][c], qf[qt][c], s, 0, 0, 0); \
            st[qt][kt] = s;                                                           \
        }                                                                             \
    __builtin_amdgcn_s_setprio(0);                                                    \
    _Pragma("unroll")                                                                 \
    for (int qt = 0; qt < 2; qt++) {                                                  \
        int qg = qbase + qt * 16 + l15;                                               \
        float pmax = -INFINITY;                                                       \
        _Pragma("unroll")                                                             \
        for (int kt = 0; kt < 2; kt++)                                                \
            _Pragma("unroll")                                                         \
            for (int r = 0; r < 4; r++) {                                             \
                int kv = kv0 + kt * 16 + hg * 4 + r;                                  \
                float v = st[qt][kt][r];                                              \
                if (kv > qg) v = -INFINITY;                                           \
                st[qt][kt][r] = v;                                                    \
                pmax = fmaxf(pmax, v);                                                \
            }                                                                         \
        pmax = fmaxf(pmax, __shfl_xor(pmax, 16));                                     \
        pmax = fmaxf(pmax, __shfl_xor(pmax, 32));                                     \
        float m_new = fmaxf(m_run[qt], pmax);                                         \
        float corr  = __expf(m_run[qt] - m_new);                                      \
        float psum  = 0.f;                                                            \
        ushort4 pk[2];                                                                \
        _Pragma("unroll")                                                             \
        for (int kt = 0; kt < 2; kt++) {                                              \
            float e0 = __expf(st[qt][kt][0] - m_new);                                 \
            float e1 = __expf(st[qt][kt][1] - m_new);                                 \
            float e2 = __expf(st[qt][kt][2] - m_new);                                 \
            float e3 = __expf(st[qt][kt][3] - m_new);                                 \
            psum += e0 + e1 + e2 + e3;                                                \
            pk[kt].x = f2bf(e0); pk[kt].y = f2bf(e1);                                 \
            pk[kt].z = f2bf(e2); pk[kt].w = f2bf(e3);                                 \
        }                                                                             \
        psum += __shfl_xor(psum, 16);                                                 \
        psum += __shfl_xor(psum, 32);                                                 \
        l_run[qt] = l_run[qt] * corr + psum;                                          \
        m_run[qt] = m_new;                                                            \
        _Pragma("unroll")                                                             \
        for (int t2 = 0; t2 < 8; t2++) acc[qt][t2] *= corr;                           \
        _Pragma("unroll")                                                             \
        for (int kt = 0; kt < 2; kt++)                                                \
            *(ushort4*)&Plds[qt][l15][kt * 16 + hg * 4] = pk[kt];                     \
    }                                                                                 \
    __builtin_amdgcn_s_setprio(1);                                                    \
    _Pragma("unroll")                                                                 \
    for (int qt = 0; qt < 2; qt++) {                                                  \
        short8 pf = *(const short8*)&Plds[qt][l15][hg * 8];                           \
        _Pragma("unroll")                                                             \
        for (int t2 = 0; t2 < 8; t2++)                                                \
            acc[qt][t2] = __builtin_amdgcn_mfma_f32_16x16x32_bf16(vf[t2], pf, acc[qt][t2], 0, 0, 0); \
    }                                                                                 \
    __builtin_amdgcn_s_setprio(0);                                                    \
} while (0)

    for (int b = 0; b < nblk; b += 2) {
        ATT_STEP(k0, k1, b);
        if (b + 1 < nblk) ATT_STEP(k1, k0, b + 1);
    }
#undef ATT_STEP

#pragma unroll
    for (int qt = 0; qt < 2; qt++) {
        float inv = 1.f / l_run[qt];
        unsigned short* orow = O + (long)(qbase + qt * 16 + l15) * NDIM + head * 128;
#pragma unroll
        for (int t2 = 0; t2 < 8; t2++) {
            ushort4 o4;
            o4.x = f2bf(acc[qt][t2][0] * inv); o4.y = f2bf(acc[qt][t2][1] * inv);
            o4.z = f2bf(acc[qt][t2][2] * inv); o4.w = f2bf(acc[qt][t2][3] * inv);
            *(ushort4*)(orow + t2 * 16 + hg * 4) = o4;
        }
    }
}

extern "C" void kernel_launch(void* const* d_in, const int* in_sizes, int n_in,
                              void* d_out, int out_size, void* d_ws, size_t ws_size,
                              hipStream_t stream) {
    const float* x  = (const float*)d_in[0];
    const float* fc = (const float*)d_in[1];
    const float* fs = (const float*)d_in[2];
    const float* wq = (const float*)d_in[3];
    const float* wk = (const float*)d_in[4];
    const float* wv = (const float*)d_in[5];
    const float* wo = (const float*)d_in[6];
    float* out = (float*)d_out;
    char* ws = (char*)d_ws;
    const size_t MB = 1024 * 1024;
    unsigned short* x_bf  = (unsigned short*)(ws + 0);        // 16MB, reused as Qbf
    unsigned short* wq_bf = (unsigned short*)(ws + 16 * MB);  // 32MB
    unsigned short* wkv_bf= (unsigned short*)(ws + 48 * MB);  // 16MB: wk (8MB) then wv (8MB), contiguous
    unsigned short* wo_bf = (unsigned short*)(ws + 64 * MB);  // 32MB
    unsigned short* Kbf   = (unsigned short*)(ws + 96 * MB);  // 4MB
    unsigned short* VT    = (unsigned short*)(ws + 100 * MB); // 4MB
    float* Q32  = (float*)(ws + 104 * MB);                    // 32MB
    float* KV32 = (float*)(ws + 136 * MB);                    // 16MB [2048][2048]: K cols 0-1023, V cols 1024-2047
    unsigned short* Qbf     = x_bf;                           // alias: x_bf dead after QKV GEMMs
    unsigned short* attn_bf = (unsigned short*)(ws + 104 * MB); // alias: Q32 dead after rope

    cvt_kernel<<<8192, 256, 0, stream>>>(x, x_bf, SEQ * NDIM);
    cvt_kernel<<<16384, 256, 0, stream>>>(wq, wq_bf, NDIM * NDIM);
    cvt_kernel<<<4096, 256, 0, stream>>>(wk, wkv_bf, NKV * HD * NDIM);
    cvt_kernel<<<4096, 256, 0, stream>>>(wv, wkv_bf + (size_t)NKV * HD * NDIM, NKV * HD * NDIM);
    cvt_kernel<<<16384, 256, 0, stream>>>(wo, wo_bf, NDIM * NDIM);

    // Q projection and fused K|V projection (N=2048 -> 256 workgroups instead of 2x128)
    gemm_bt<<<dim3(NDIM / 128, SEQ / 128), 256, 0, stream>>>(x_bf, wq_bf, Q32, SEQ, NDIM, NDIM);
    gemm_bt<<<dim3(2048 / 128, SEQ / 128), 256, 0, stream>>>(x_bf, wkv_bf, KV32, SEQ, 2048, NDIM);

    rope_kernel<<<16384, 256, 0, stream>>>(Q32, fc, fs, Qbf, 31, 11, NDIM, NDIM, ATT_SCALE);
    rope_kernel<<<4096, 256, 0, stream>>>(KV32, fc, fs, Kbf, 7, 9, 2048, 1024, 1.0f);
    transpose_v<<<dim3(SEQ / 32, 1024 / 32), dim3(32, 8), 0, stream>>>(KV32, VT);

    attn_kernel<<<NH * (SEQ / 32), 64, 0, stream>>>(Qbf, Kbf, VT, attn_bf);

    gemm_bt<<<dim3(NDIM / 128, SEQ / 128), 256, 0, stream>>>(attn_bf, wo_bf, out, SEQ, NDIM, NDIM);
}